// Round 5
// baseline (362.971 us; speedup 1.0000x reference)
//
#include <hip/hip_runtime.h>
#include <hip/hip_bf16.h>

// ---------------------------------------------------------------------------
// Goal_Conditioned_Policies: conv(3->32,s2) relu, conv(32->64,s2) relu,
// mean-pool, MLP chain with per-sample einsum, softmax.
// B=4096, x[4096,3,64,64] fp32, C[4096,50,50] fp32, out [4096,50] fp32.
//
// Round 9: barrier diet. k_conv runs 1 block/CU (153KB LDS) so every
//   s_barrier exposes full-CU sync latency. im2col->conv1 is WAVE-LOCAL
//   (im2col thread p writes a1[p]; wave w's conv1 reads slots w*64..w*64+63
//   = its own lanes) -> the 2 barriers between them are dropped; compiler
//   inserts the wave-local lgkmcnt waits. 6 -> 4 barriers/iter.
//   vmcnt counts re-derived: queue/wave = {ST_old, A x3, B x4, ST} ->
//   VM4 drains A, VM1 drains B. Pooled store redistributed 1-per-wave so
//   counts are wave-uniform; prologue dummy store (+asm fences pinning
//   order) makes iter-0 match steady state. k_prep / k_mlp unchanged.
// ---------------------------------------------------------------------------

typedef __attribute__((ext_vector_type(8)))  short short8;
typedef __attribute__((ext_vector_type(4)))  float floatx4;
typedef __attribute__((ext_vector_type(16))) float floatx16;

#define AS1 __attribute__((address_space(1)))
#define AS3 __attribute__((address_space(3)))

#define BAR_LGKM() asm volatile("s_waitcnt lgkmcnt(0)\ns_barrier" ::: "memory")
#define BAR_FULL() asm volatile("s_waitcnt vmcnt(0) lgkmcnt(0)\ns_barrier" ::: "memory")
// counted waits: VM4 -> A(s) ready (drains {ST_old,A0..A2,B0} from 8+1);
//                VM1 -> B(s) ready (leaves only the newest store)
#define BAR_VM4()  asm volatile("s_waitcnt vmcnt(4) lgkmcnt(0)\ns_barrier" ::: "memory")
#define BAR_VM1()  asm volatile("s_waitcnt vmcnt(1) lgkmcnt(0)\ns_barrier" ::: "memory")
#define CFENCE()   asm volatile("" ::: "memory")

__device__ __forceinline__ short f2bf(float f) {
    unsigned u = __float_as_uint(f);
    u += 0x7fffu + ((u >> 16) & 1u);   // round-to-nearest-even
    return (short)(u >> 16);
}

__device__ __forceinline__ unsigned pkbf2(float a, float b) {
    float2 fp; fp.x = a; fp.y = b;
    __hip_bfloat162 bb = __float22bfloat162_rn(fp);
    return *(unsigned*)&bb;
}

// ---------------------------------------------------------------------------
// d_ws layout (bytes):
//   0      : conv2 pack bf16 [pos][oc=64][ic=32]      36864
//   36864  : conv1 pack bf16 [oc=32][k=32]             2048
//   40960  : MLP block (staged verbatim to LDS)      118784 (=29*4096)
//   163840 : pooled fp32 [4096][64]
// ---------------------------------------------------------------------------
#define WS_MLP_B    40960
#define WS_BIAS_B   (40960 + 115712)
#define WS_POOL_B   163840

__global__ void k_prep(const float* __restrict__ cw2, const float* __restrict__ cw1,
                       const float* __restrict__ ew,  const float* __restrict__ w1,
                       const float* __restrict__ w2,  const float* __restrict__ w3,
                       const float* __restrict__ w4,  const float* __restrict__ w5,
                       const float* __restrict__ ow,  const float* __restrict__ eb,
                       const float* __restrict__ b1,  const float* __restrict__ b2,
                       const float* __restrict__ b3,  const float* __restrict__ b4,
                       const float* __restrict__ b5,  const float* __restrict__ ob,
                       short* __restrict__ packw, float* __restrict__ biasout) {
    const int idx = blockIdx.x * 256 + threadIdx.x;
    if (idx < 18432) {                       // conv2: [pos][oc][ic]
        const int ic  = idx & 31;
        const int oc  = (idx >> 5) & 63;
        const int pos = idx >> 11;
        packw[idx] = f2bf(cw2[oc * 288 + ic * 9 + pos]);
    } else if (idx < 19456) {                // conv1: [oc][k=32]
        const int j  = idx - 18432;
        const int k  = j & 31;
        const int oc = j >> 5;
        packw[idx] = (k < 27) ? f2bf(cw1[oc * 27 + k]) : (short)0;
    } else if (idx < 77312) {                // MLP weights (transposed, padded)
        const int e = idx - 19456;
        short v;
        if (e < 9216)        { const int n = e / 72,  kk = e - n * 72;
            v = (kk < 64) ? f2bf(ew[kk * 128 + n]) : (short)0; }
        else if (e < 17920)  { const int r = e - 9216;  const int n = r / 136, kk = r - n * 136;
            v = (kk < 128 && n < 50) ? f2bf(w1[kk * 50 + n]) : (short)0; }
        else if (e < 27136)  { const int r = e - 17920; const int n = r / 72,  kk = r - n * 72;
            v = (kk < 50) ? f2bf(w2[kk * 128 + n]) : (short)0; }
        else if (e < 44032)  { const int r = e - 27136; const int n = r / 264, kk = r - n * 264;
            v = (kk < 256) ? f2bf(w3[kk * 64 + n]) : (short)0; }
        else if (e < 48640)  { const int r = e - 44032; const int n = r / 72,  kk = r - n * 72;
            v = (kk < 64) ? f2bf(w4[kk * 64 + n]) : (short)0; }
        else if (e < 53248)  { const int r = e - 48640; const int n = r / 72,  kk = r - n * 72;
            v = (kk < 64) ? f2bf(w5[kk * 64 + n]) : (short)0; }
        else                 { const int r = e - 53248; const int n = r / 72,  kk = r - n * 72;
            v = (kk < 64 && n < 50) ? f2bf(ow[kk * 50 + n]) : (short)0; }
        packw[20480 + e] = v;
    } else if (idx < 77888) {                // biases fp32, padded
        const int j = idx - 77312;
        float v;
        if (j < 128)      v = eb[j];
        else if (j < 192) v = (j - 128 < 50) ? b1[j - 128] : 0.f;
        else if (j < 320) v = b2[j - 192];
        else if (j < 384) v = b3[j - 320];
        else if (j < 448) v = b4[j - 384];
        else if (j < 512) v = b5[j - 448];
        else              v = (j - 512 < 50) ? ob[j - 512] : 0.f;
        biasout[j] = v;
    }
}

// ---------------------------------------------------------------------------
// k_conv: fused conv1(MFMA) + conv2(MFMA) + mean pool, 4 barriers/iter.
// LDS:
//   0      xsA fp32 [3][32][64]  (x rows 0..31)          24576
//   24576  xsB fp32 [3][33][64]  (x rows 31..63)         25344
//   49920  a1  im2col bf16 [512][80]   (aliased poolbuf) 40960
//   90880  h1b conv1-out bf16, 32 rows x 2064            66048
//   total 156928
// ---------------------------------------------------------------------------
#define XS_OFF   0
#define XSB_OFF  24576
#define A1_OFF   49920
#define A1STR    80
#define H1_OFF   90880
#define ROWB     2064
#define SMEM_SZ  156928
#define SPB      16

__global__ __launch_bounds__(512, 2) void k_conv(
    const float* __restrict__ x,    const float* __restrict__ c1b,
    const short* __restrict__ packw, const float* __restrict__ c2b,
    float* __restrict__ pooled)
{
    __shared__ __align__(16) char smem[SMEM_SZ];
    float* xs      = (float*)(smem + XS_OFF);    // A: [3][32][64]
    float* xsb     = (float*)(smem + XSB_OFF);   // B: [3][33][64]
    char*  a1      = smem + A1_OFF;
    char*  h1b     = smem + H1_OFF;
    float* poolbuf = (float*)(smem + A1_OFF);

    const int tid  = threadIdx.x;
    const int lane = tid & 63;
    const int w    = tid >> 6;

    const int col = lane & 31;
    const int ss  = lane >> 5;

    const int nt  = w & 1;
    const int ox2 = lane & 15;
    const int oyb = (lane >> 4) & 1;
    const int ocn = nt * 32 + col;
    const float bias2 = c2b[ocn];

    short8 z8;
    #pragma unroll
    for (int i = 0; i < 8; ++i) z8[i] = 0;

    short8 bfr[9][2];
    #pragma unroll
    for (int pos = 0; pos < 9; ++pos)
        #pragma unroll
        for (int h = 0; h < 2; ++h)
            bfr[pos][h] = *(const short8*)(packw + (pos * 64 + ocn) * 32 + h * 16 + ss * 8);

    const short* w1p = packw + 18432;
    short8 w1f[2];
    #pragma unroll
    for (int k = 0; k < 2; ++k)
        w1f[k] = *(const short8*)(w1p + col * 32 + k * 16 + ss * 8);

    float2 b1p[8];
    #pragma unroll
    for (int rp = 0; rp < 8; ++rp)
        b1p[rp] = *(const float2*)(c1b + ((rp & 1) * 2 + (rp >> 1) * 8 + 4 * ss));

    int  sbv[3][2];
    bool okx[3];
    #pragma unroll
    for (int kx = 0; kx < 3; ++kx) {
        const int ph   = (kx + 1) & 1;
        const int xh   = ox2 - (kx == 0 ? 1 : 0);
        const int slot = ph * 16 + xh;
        const int swz  = (slot >> 1) & 3;
        okx[kx] = (xh >= 0);
        #pragma unroll
        for (int h = 0; h < 2; ++h)
            sbv[kx][h] = slot * 64 + (((ss + 2 * h) ^ swz) << 4);
    }

    const int slotpx = ((col & 1) << 4) + (col >> 1);
    const int wswz   = (slotpx >> 1) & 3;
    const int wbase  = slotpx * 64 + ss * 8;

    // ---- counted-vmcnt staging via global_load_lds (wave-uniform dest) ----
    // A: rows 0..31 per ic, 24 x 1KB chunks (3/wave), dest xsA [ic][32][64].
    auto issueA = [&](int bb) {
        const char* g = (const char*)(x + (size_t)bb * 12288);
        #pragma unroll
        for (int i = 0; i < 3; ++i) {
            const int idx = w * 3 + i;             // 0..23
            const int ic  = idx >> 3, blk = idx & 7;
            const int so  = ic * 16384 + blk * 1024;
            const int dof = ic * 8192  + blk * 1024;
            __builtin_amdgcn_global_load_lds(
                (const AS1 unsigned int*)(g + so + lane * 16),
                (AS3 unsigned int*)(smem + XS_OFF + dof), 16, 0, 0);
        }
    };
    // B: rows 31..63 per ic (row 31 duplicated). 27 real 1KB chunks padded to
    // 32 (4/wave); pad chunks duplicate chunks 0..4 (same src+dst, L2-hot).
    auto issueB = [&](int bb) {
        const char* g = (const char*)(x + (size_t)bb * 12288);
        #pragma unroll
        for (int i = 0; i < 4; ++i) {
            int idx = w * 4 + i;                   // 0..31
            if (idx >= 27) idx -= 27;              // dummy -> dup 0..4
            const int ic = idx / 9, k = idx - ic * 9;
            const int so  = ic * 16384 + ((k == 0) ? 7936 : 8192 + (k - 1) * 1024);
            const int dof = ic * 8448  + ((k == 0) ? 0    : 256  + (k - 1) * 1024);
            __builtin_amdgcn_global_load_lds(
                (const AS1 unsigned int*)(g + so + lane * 16),
                (AS3 unsigned int*)(smem + XSB_OFF + dof), 16, 0, 0);
        }
    };

    auto im2col = [&](int half) {
        const int p  = tid;
        const int oy = half * 16 + (p >> 5);
        const int ox = p & 31;
        const int bx = 2 * ox;
        float f[32];
        #pragma unroll
        for (int ic = 0; ic < 3; ++ic) {
            #pragma unroll
            for (int ky = 0; ky < 3; ++ky) {
                const int  iy  = 2 * oy + ky - 1;
                const bool oky = iy >= 0;
                const float* rowp = (half == 0)
                    ? xs  + ic * 2048 + (oky ? iy : 0) * 64      // rows 0..31
                    : xsb + ic * 2112 + (iy - 31) * 64;          // rows 31..63
                const float2 p12 = *(const float2*)(rowp + bx);
                const float2 pm  = *(const float2*)(rowp + (bx >= 2 ? bx - 2 : 0));
                const int k = ic * 9 + ky * 3;
                f[k + 0] = (oky && ox > 0) ? pm.y : 0.f;
                f[k + 1] = oky ? p12.x : 0.f;
                f[k + 2] = oky ? p12.y : 0.f;
            }
        }
        f[27] = 0.f; f[28] = 0.f; f[29] = 0.f; f[30] = 0.f; f[31] = 0.f;
        unsigned pk[16];
        #pragma unroll
        for (int t = 0; t < 16; ++t) pk[t] = pkbf2(f[2 * t], f[2 * t + 1]);
        uint4* dst = (uint4*)(a1 + p * A1STR);
        dst[0] = make_uint4(pk[0],  pk[1],  pk[2],  pk[3]);
        dst[1] = make_uint4(pk[4],  pk[5],  pk[6],  pk[7]);
        dst[2] = make_uint4(pk[8],  pk[9],  pk[10], pk[11]);
        dst[3] = make_uint4(pk[12], pk[13], pk[14], pk[15]);
    };

    auto conv1_mfma = [&](int half) {
        #pragma unroll
        for (int i = 0; i < 2; ++i) {
            const int t = w * 2 + i;
            const char* abase = a1 + (t * 32 + col) * A1STR + ss * 16;
            const short8 bf0 = *(const short8*)(abase);
            const short8 bf1 = *(const short8*)(abase + 32);
            floatx16 acc;
            #pragma unroll
            for (int r = 0; r < 16; ++r) acc[r] = 0.f;
            acc = __builtin_amdgcn_mfma_f32_32x32x16_bf16(w1f[0], bf0, acc, 0, 0, 0);
            acc = __builtin_amdgcn_mfma_f32_32x32x16_bf16(w1f[1], bf1, acc, 0, 0, 0);
            const int oyg = half * 16 + t;
            char* hb = h1b + oyg * ROWB + wbase;
            #pragma unroll
            for (int rp = 0; rp < 8; ++rp) {
                const unsigned u = pkbf2(fmaxf(acc[2 * rp]     + b1p[rp].x, 0.f),
                                         fmaxf(acc[2 * rp + 1] + b1p[rp].y, 0.f));
                const int off = (((rp >> 1) ^ wswz) << 4) + (rp & 1) * 4;
                *(unsigned*)(hb + off) = u;
            }
        }
    };

    // prologue: A(0)+B(0) in flight + dummy store (uniform vmcnt queue:
    // every wave holds {A x3, B x4, ST x1} entering each iteration).
    issueA(blockIdx.x);
    issueB(blockIdx.x);
    CFENCE();
    if (lane < 8) pooled[(size_t)blockIdx.x * 64 + w * 8 + lane] = 0.f;
    CFENCE();

    #pragma unroll 1
    for (int s = 0; s < SPB; ++s) {
        const int b  = blockIdx.x + (s << 8);
        const int bn = (s + 1 < SPB) ? b + 256 : b;   // tail: reload self (uniform counts)

        BAR_VM4();            // A(s) ready; all prior LDS reads drained
        im2col(0);            // reads xsA(s), writes a1 (own slot)
        conv1_mfma(0);        // reads a1 (own wave's slots), writes h1b rows 0..15
        BAR_VM1();            // B(s) ready; xsA(s) consumed block-wide
        issueA(bn);           // window: conv1(1)+conv2 (~60% of iter)
        im2col(1);            // reads xsB(s)
        conv1_mfma(1);        // writes h1b rows 16..31
        BAR_LGKM();           // h1b complete; xsB(s) consumed
        issueB(bn);           // window: conv2+next im2col(0)/conv1(0)

        const int t0 = w >> 1;
        float pool = 0.f;
        floatx16 acc0, acc1;
        #pragma unroll
        for (int r = 0; r < 16; ++r) { acc0[r] = 0.f; acc1[r] = 0.f; }
        #pragma unroll
        for (int ky = 0; ky < 3; ++ky) {
            #pragma unroll
            for (int kx = 0; kx < 3; ++kx) {
                const int  iy0 = t0 * 4 + oyb * 2 + ky - 1;
                const bool ok0 = okx[kx] && (iy0 >= 0);
                const bool ok1 = okx[kx];
                const int  ba0 = iy0 * ROWB;
                const int  ba1 = ba0 + 16 * ROWB;
                #pragma unroll
                for (int h = 0; h < 2; ++h) {
                    const int so = sbv[kx][h];
                    short8 a0v = ok0 ? *(const short8*)(h1b + ba0 + so) : z8;
                    short8 a1v = ok1 ? *(const short8*)(h1b + ba1 + so) : z8;
                    const short8 bf = bfr[ky * 3 + kx][h];
                    acc0 = __builtin_amdgcn_mfma_f32_32x32x16_bf16(a0v, bf, acc0, 0, 0, 0);
                    acc1 = __builtin_amdgcn_mfma_f32_32x32x16_bf16(a1v, bf, acc1, 0, 0, 0);
                }
            }
        }
        #pragma unroll
        for (int r = 0; r < 16; ++r) {
            pool += fmaxf(acc0[r] + bias2, 0.f);
            pool += fmaxf(acc1[r] + bias2, 0.f);
        }
        pool += __shfl_xor(pool, 32, 64);
        if (lane < 32) poolbuf[w * 32 + lane] = pool;
        BAR_LGKM();           // poolbuf visible
        // distributed pooled store: 1 store per wave (uniform vmcnt)
        if (lane < 8) {
            const int ch = w * 8 + lane;
            const int g = ch >> 5, c = ch & 31;
            pooled[(size_t)b * 64 + ch] =
                (poolbuf[(g    ) * 32 + c] + poolbuf[(g + 2) * 32 + c] +
                 poolbuf[(g + 4) * 32 + c] + poolbuf[(g + 6) * 32 + c]) * (1.f / 256.f);
        }
        // next BAR_VM4 (lgkmcnt(0)+barrier) retires poolbuf reads before
        // wave0's im2col(0) overwrites the aliased a1 bytes
    }
}

// ---------------------------------------------------------------------------
// k_mlp: 256 blocks x 16 samples, all shared-weight layers via MFMA 16x16x32.
// (unchanged from R4)
// ---------------------------------------------------------------------------
#define ML_BIAS_B 115712
#define ML_P_SH   59392
#define ML_A_SH   60544
#define ML_B_SH   64768
#define ML_Z_F    34496
#define ML_SMEM   142336

__global__ __launch_bounds__(256, 1) void k_mlp(
    const char* __restrict__ wsblk,   // d_ws + WS_MLP_B (staged verbatim)
    const float* __restrict__ pooled, const float* __restrict__ C,
    float* __restrict__ out)
{
    __shared__ __align__(16) char smem[ML_SMEM];
    short*       Sw   = (short*)smem;
    const short* S    = (const short*)smem;
    const float* Bias = (const float*)(smem + ML_BIAS_B);
    float*       Zf   = (float*)smem;     // indexed from ML_Z_F

    const int tid    = threadIdx.x;
    const int lane   = tid & 63;
    const int w      = tid >> 6;
    const int n16    = lane & 15;
    const int q      = lane >> 4;
    const int tile16 = blockIdx.x * 16;

    // ---- stage weights+biases: 29 * 4096 B, exact, via global_load_lds ----
    #pragma unroll
    for (int i = 0; i < 29; ++i) {
        const int off = i * 4096 + w * 1024;
        __builtin_amdgcn_global_load_lds(
            (const AS1 unsigned int*)(wsblk + off + lane * 16),
            (AS3 unsigned int*)(smem + off), 16, 0, 0);
    }
    // ---- stage pooled tile -> P bf16 [16][72] ----
    {
        const float4 pv = *(const float4*)(pooled + tile16 * 64 + tid * 4);
        const int s = tid >> 4, k = (tid & 15) * 4;
        uint2 u;
        u.x = pkbf2(pv.x, pv.y);
        u.y = pkbf2(pv.z, pv.w);
        *(uint2*)(Sw + ML_P_SH + s * 72 + k) = u;
    }
    BAR_FULL();   // weights + pooled visible

    // ---- generic MFMA layer ----
    auto layer = [&](int inOff, int inPitch, int K, int wOff, int nTiles,
                     int biasOff, int outOff, bool isOut) {
        #pragma unroll
        for (int nt = w; nt < nTiles; nt += 4) {
            floatx4 acc;
            acc[0] = 0.f; acc[1] = 0.f; acc[2] = 0.f; acc[3] = 0.f;
            const int kp = K + 8;
            #pragma unroll
            for (int kc = 0; kc < 8; ++kc) {        // K/32 chunks (max 8)
                if (kc * 32 >= K) break;
                const short8 aF = *(const short8*)(S + inOff + n16 * inPitch + kc * 32 + q * 8);
                const short8 bF = *(const short8*)(S + wOff + (nt * 16 + n16) * kp + kc * 32 + q * 8);
                acc = __builtin_amdgcn_mfma_f32_16x16x32_bf16(aF, bF, acc, 0, 0, 0);
            }
            const int   n  = nt * 16 + n16;
            const float bv = Bias[biasOff + n];
            #pragma unroll
            for (int r = 0; r < 4; ++r) {
                const int   m = q * 4 + r;
                const float v = fmaxf(acc[r] + bv, 0.f);
                if (isOut) Zf[ML_Z_F + m * 68 + n] = (n < 50) ? v : -1e30f;
                else       Sw[outOff + m * 264 + n] = f2bf(v);
            }
        }
    };

    layer(ML_P_SH, 72, 64, 0, 8, 0, ML_A_SH, false);            // enc -> x1 (A 0..127)
    BAR_LGKM();
    layer(ML_A_SH, 264, 128, 9216, 4, 128, ML_B_SH, false);     // f1 -> x2 (B 0..63)
    BAR_LGKM();

    // ---- einsum: e[s][i] = sum_j C[b][i][j] * x2[s][j], 800 items ----
    #pragma unroll
    for (int r = 0; r < 4; ++r) {
        const int item = tid + r * 256;
        if (item < 800) {
            const int s = (item * 1311) >> 16;      // item/50, exact for <800
            const int i = item - s * 50;
            const float* Cp = C + (size_t)(tile16 + s) * 2500 + i * 50;
            float e = 0.f;
            #pragma unroll
            for (int j2 = 0; j2 < 25; ++j2) {
                const float2   cc = *(const float2*)(Cp + 2 * j2);
                const unsigned u  = *(const unsigned*)(S + ML_B_SH + s * 264 + 2 * j2);
                e += cc.x * __uint_as_float(u << 16)
                   + cc.y * __uint_as_float(u & 0xffff0000u);
            }
            Sw[ML_B_SH + s * 264 + 64 + i] = f2bf(e);
        }
    }
    if ((tid & 15) < 14)                              // zero-pad e[50..63]
        Sw[ML_B_SH + (tid >> 4) * 264 + 64 + 50 + (tid & 15)] = 0;
    BAR_LGKM();

    layer(ML_B_SH + 64, 264, 64, 17920, 8, 192, ML_A_SH + 128, false); // f2 -> x3 (A 128..255)
    BAR_LGKM();
    layer(ML_A_SH, 264, 256, 27136, 4, 320, ML_B_SH, false);    // f3 (concat) -> x5 (B 0..63)
    BAR_LGKM();
    layer(ML_B_SH, 264, 64, 44032, 4, 384, ML_B_SH + 64, false);// f4 -> x6 (B 64..127)
    BAR_LGKM();
    layer(ML_B_SH + 64, 264, 64, 48640, 4, 448, ML_B_SH + 128, false); // f5 -> x7
    BAR_LGKM();
    layer(ML_B_SH + 128, 264, 64, 53248, 4, 512, 0, true);      // out -> Z (fp32)
    BAR_LGKM();

    // ---- softmax: 16 threads per sample, 4 logits each, width-16 shuffles ----
    {
        const int s = tid >> 4, g = tid & 15;
        const float4 zv = *(const float4*)(Zf + ML_Z_F + s * 68 + g * 4);
        float m = fmaxf(fmaxf(zv.x, zv.y), fmaxf(zv.z, zv.w));
        #pragma unroll
        for (int o = 8; o > 0; o >>= 1) m = fmaxf(m, __shfl_xor(m, o, 16));
        float4 p;
        p.x = __expf(zv.x - m); p.y = __expf(zv.y - m);
        p.z = __expf(zv.z - m); p.w = __expf(zv.w - m);
        float sum = p.x + p.y + p.z + p.w;
        #pragma unroll
        for (int o = 8; o > 0; o >>= 1) sum += __shfl_xor(sum, o, 16);
        const float inv = 1.f / sum;
        float* po = out + (size_t)(tile16 + s) * 50 + g * 4;
        const int j = g * 4;
        if (j     < 50) po[0] = p.x * inv;
        if (j + 1 < 50) po[1] = p.y * inv;
        if (j + 2 < 50) po[2] = p.z * inv;
        if (j + 3 < 50) po[3] = p.w * inv;
    }
}

// ---------------------------------------------------------------------------
extern "C" void kernel_launch(void* const* d_in, const int* in_sizes, int n_in,
                              void* d_out, int out_size, void* d_ws, size_t ws_size,
                              hipStream_t stream) {
    (void)in_sizes; (void)n_in; (void)out_size; (void)ws_size;
    const float* x   = (const float*)d_in[0];
    const float* Cm  = (const float*)d_in[1];
    const float* c1w = (const float*)d_in[2];
    const float* c1b = (const float*)d_in[3];
    const float* c2w = (const float*)d_in[4];
    const float* c2b = (const float*)d_in[5];
    const float* ew  = (const float*)d_in[6];
    const float* ebv = (const float*)d_in[7];
    const float* f1w = (const float*)d_in[8];
    const float* f1b = (const float*)d_in[9];
    const float* f2w = (const float*)d_in[10];
    const float* f2b = (const float*)d_in[11];
    const float* f3w = (const float*)d_in[12];
    const float* f3b = (const float*)d_in[13];
    const float* f4w = (const float*)d_in[14];
    const float* f4b = (const float*)d_in[15];
    const float* f5w = (const float*)d_in[16];
    const float* f5b = (const float*)d_in[17];
    const float* ow  = (const float*)d_in[18];
    const float* ob  = (const float*)d_in[19];

    short* packw   = (short*)d_ws;
    float* biasout = (float*)((char*)d_ws + WS_BIAS_B);
    float* pooled  = (float*)((char*)d_ws + WS_POOL_B);
    const char* wsblk = (const char*)d_ws + WS_MLP_B;
    float* out     = (float*)d_out;

    hipLaunchKernelGGL(k_prep, dim3(305), dim3(256), 0, stream,
                       c2w, c1w, ew, f1w, f2w, f3w, f4w, f5w, ow,
                       ebv, f1b, f2b, f3b, f4b, f5b, ob, packw, biasout);
    hipLaunchKernelGGL(k_conv, dim3(256), dim3(512), 0, stream,
                       x, c1b, packw, c2b, pooled);
    hipLaunchKernelGGL(k_mlp,  dim3(256), dim3(256), 0, stream,
                       wsblk, pooled, Cm, out);
}

// Round 6
// 356.037 us; speedup vs baseline: 1.0195x; 1.0195x over previous
//
#include <hip/hip_runtime.h>
#include <hip/hip_bf16.h>

// ---------------------------------------------------------------------------
// Goal_Conditioned_Policies: conv(3->32,s2) relu, conv(32->64,s2) relu,
// mean-pool, MLP chain with per-sample einsum, softmax.
// B=4096, x[4096,3,64,64] fp32, C[4096,50,50] fp32, out [4096,50] fp32.
//
// Round 10: cross-sample phase fusion. k_conv phases were serial and each
//   bound by its own pipe (LDS ~3.5us/sample total, MFMA 0.7, VALU 1.3 vs
//   6.25us/iter). im2col(0) of sample s+1 is fused into the conv2(s) region
//   (disjoint LDS: a1 vs h1b; complementary pipes) so the scheduler
//   interleaves them. poolbuf moved to dedicated LDS (a1 live during conv2).
//   3 barriers/iter: VM4 (B ready), FULL (h1b done + A ready; queue is old),
//   LGKM (conv2 retired). Queue traced: steady {B4,ST,A3}; prologue dummy ST
//   + vmcnt(5) A-wait + lgkm barrier before first issueA. launch_bounds
//   (512,1) for merged-region VGPR headroom. k_prep / k_mlp unchanged.
// ---------------------------------------------------------------------------

typedef __attribute__((ext_vector_type(8)))  short short8;
typedef __attribute__((ext_vector_type(4)))  float floatx4;
typedef __attribute__((ext_vector_type(16))) float floatx16;

#define AS1 __attribute__((address_space(1)))
#define AS3 __attribute__((address_space(3)))

#define BAR_LGKM() asm volatile("s_waitcnt lgkmcnt(0)\ns_barrier" ::: "memory")
#define BAR_FULL() asm volatile("s_waitcnt vmcnt(0) lgkmcnt(0)\ns_barrier" ::: "memory")
#define BAR_VM4()  asm volatile("s_waitcnt vmcnt(4) lgkmcnt(0)\ns_barrier" ::: "memory")
#define BAR_VM5()  asm volatile("s_waitcnt vmcnt(5) lgkmcnt(0)\ns_barrier" ::: "memory")
#define CFENCE()   asm volatile("" ::: "memory")

__device__ __forceinline__ short f2bf(float f) {
    unsigned u = __float_as_uint(f);
    u += 0x7fffu + ((u >> 16) & 1u);   // round-to-nearest-even
    return (short)(u >> 16);
}

__device__ __forceinline__ unsigned pkbf2(float a, float b) {
    float2 fp; fp.x = a; fp.y = b;
    __hip_bfloat162 bb = __float22bfloat162_rn(fp);
    return *(unsigned*)&bb;
}

// ---------------------------------------------------------------------------
// d_ws layout (bytes):
//   0      : conv2 pack bf16 [pos][oc=64][ic=32]      36864
//   36864  : conv1 pack bf16 [oc=32][k=32]             2048
//   40960  : MLP block (staged verbatim to LDS)      118784 (=29*4096)
//   163840 : pooled fp32 [4096][64]
// ---------------------------------------------------------------------------
#define WS_MLP_B    40960
#define WS_BIAS_B   (40960 + 115712)
#define WS_POOL_B   163840

__global__ void k_prep(const float* __restrict__ cw2, const float* __restrict__ cw1,
                       const float* __restrict__ ew,  const float* __restrict__ w1,
                       const float* __restrict__ w2,  const float* __restrict__ w3,
                       const float* __restrict__ w4,  const float* __restrict__ w5,
                       const float* __restrict__ ow,  const float* __restrict__ eb,
                       const float* __restrict__ b1,  const float* __restrict__ b2,
                       const float* __restrict__ b3,  const float* __restrict__ b4,
                       const float* __restrict__ b5,  const float* __restrict__ ob,
                       short* __restrict__ packw, float* __restrict__ biasout) {
    const int idx = blockIdx.x * 256 + threadIdx.x;
    if (idx < 18432) {                       // conv2: [pos][oc][ic]
        const int ic  = idx & 31;
        const int oc  = (idx >> 5) & 63;
        const int pos = idx >> 11;
        packw[idx] = f2bf(cw2[oc * 288 + ic * 9 + pos]);
    } else if (idx < 19456) {                // conv1: [oc][k=32]
        const int j  = idx - 18432;
        const int k  = j & 31;
        const int oc = j >> 5;
        packw[idx] = (k < 27) ? f2bf(cw1[oc * 27 + k]) : (short)0;
    } else if (idx < 77312) {                // MLP weights (transposed, padded)
        const int e = idx - 19456;
        short v;
        if (e < 9216)        { const int n = e / 72,  kk = e - n * 72;
            v = (kk < 64) ? f2bf(ew[kk * 128 + n]) : (short)0; }
        else if (e < 17920)  { const int r = e - 9216;  const int n = r / 136, kk = r - n * 136;
            v = (kk < 128 && n < 50) ? f2bf(w1[kk * 50 + n]) : (short)0; }
        else if (e < 27136)  { const int r = e - 17920; const int n = r / 72,  kk = r - n * 72;
            v = (kk < 50) ? f2bf(w2[kk * 128 + n]) : (short)0; }
        else if (e < 44032)  { const int r = e - 27136; const int n = r / 264, kk = r - n * 264;
            v = (kk < 256) ? f2bf(w3[kk * 64 + n]) : (short)0; }
        else if (e < 48640)  { const int r = e - 44032; const int n = r / 72,  kk = r - n * 72;
            v = (kk < 64) ? f2bf(w4[kk * 64 + n]) : (short)0; }
        else if (e < 53248)  { const int r = e - 48640; const int n = r / 72,  kk = r - n * 72;
            v = (kk < 64) ? f2bf(w5[kk * 64 + n]) : (short)0; }
        else                 { const int r = e - 53248; const int n = r / 72,  kk = r - n * 72;
            v = (kk < 64 && n < 50) ? f2bf(ow[kk * 50 + n]) : (short)0; }
        packw[20480 + e] = v;
    } else if (idx < 77888) {                // biases fp32, padded
        const int j = idx - 77312;
        float v;
        if (j < 128)      v = eb[j];
        else if (j < 192) v = (j - 128 < 50) ? b1[j - 128] : 0.f;
        else if (j < 320) v = b2[j - 192];
        else if (j < 384) v = b3[j - 320];
        else if (j < 448) v = b4[j - 384];
        else if (j < 512) v = b5[j - 448];
        else              v = (j - 512 < 50) ? ob[j - 512] : 0.f;
        biasout[j] = v;
    }
}

// ---------------------------------------------------------------------------
// k_conv: fused conv1(MFMA) + conv2(MFMA) + mean pool; conv2(s) fused with
// im2col0(s+1). LDS:
//   0      xsA fp32 [3][32][64]  (x rows 0..31)          24576
//   24576  xsB fp32 [3][33][64]  (x rows 31..63)         25344
//   49920  a1  im2col bf16 [512][80]                     40960
//   90880  h1b conv1-out bf16, 32 rows x 2064            66048
//   156928 poolbuf fp32 [256]                             1024
//   total 157952
// ---------------------------------------------------------------------------
#define XS_OFF   0
#define XSB_OFF  24576
#define A1_OFF   49920
#define A1STR    80
#define H1_OFF   90880
#define ROWB     2064
#define POOL_OFF 156928
#define SMEM_SZ  157952
#define SPB      16

__global__ __launch_bounds__(512, 1) void k_conv(
    const float* __restrict__ x,    const float* __restrict__ c1b,
    const short* __restrict__ packw, const float* __restrict__ c2b,
    float* __restrict__ pooled)
{
    __shared__ __align__(16) char smem[SMEM_SZ];
    float* xs      = (float*)(smem + XS_OFF);    // A: [3][32][64]
    float* xsb     = (float*)(smem + XSB_OFF);   // B: [3][33][64]
    char*  a1      = smem + A1_OFF;
    char*  h1b     = smem + H1_OFF;
    float* poolbuf = (float*)(smem + POOL_OFF);

    const int tid  = threadIdx.x;
    const int lane = tid & 63;
    const int w    = tid >> 6;

    const int col = lane & 31;
    const int ss  = lane >> 5;

    const int nt  = w & 1;
    const int ox2 = lane & 15;
    const int oyb = (lane >> 4) & 1;
    const int ocn = nt * 32 + col;
    const float bias2 = c2b[ocn];

    short8 z8;
    #pragma unroll
    for (int i = 0; i < 8; ++i) z8[i] = 0;

    short8 bfr[9][2];
    #pragma unroll
    for (int pos = 0; pos < 9; ++pos)
        #pragma unroll
        for (int h = 0; h < 2; ++h)
            bfr[pos][h] = *(const short8*)(packw + (pos * 64 + ocn) * 32 + h * 16 + ss * 8);

    const short* w1p = packw + 18432;
    short8 w1f[2];
    #pragma unroll
    for (int k = 0; k < 2; ++k)
        w1f[k] = *(const short8*)(w1p + col * 32 + k * 16 + ss * 8);

    float2 b1p[8];
    #pragma unroll
    for (int rp = 0; rp < 8; ++rp)
        b1p[rp] = *(const float2*)(c1b + ((rp & 1) * 2 + (rp >> 1) * 8 + 4 * ss));

    int  sbv[3][2];
    bool okx[3];
    #pragma unroll
    for (int kx = 0; kx < 3; ++kx) {
        const int ph   = (kx + 1) & 1;
        const int xh   = ox2 - (kx == 0 ? 1 : 0);
        const int slot = ph * 16 + xh;
        const int swz  = (slot >> 1) & 3;
        okx[kx] = (xh >= 0);
        #pragma unroll
        for (int h = 0; h < 2; ++h)
            sbv[kx][h] = slot * 64 + (((ss + 2 * h) ^ swz) << 4);
    }

    const int slotpx = ((col & 1) << 4) + (col >> 1);
    const int wswz   = (slotpx >> 1) & 3;
    const int wbase  = slotpx * 64 + ss * 8;

    // ---- staging via global_load_lds (wave-uniform dest), counted vmcnt ----
    auto issueA = [&](int bb) {
        const char* g = (const char*)(x + (size_t)bb * 12288);
        #pragma unroll
        for (int i = 0; i < 3; ++i) {
            const int idx = w * 3 + i;             // 0..23
            const int ic  = idx >> 3, blk = idx & 7;
            const int so  = ic * 16384 + blk * 1024;
            const int dof = ic * 8192  + blk * 1024;
            __builtin_amdgcn_global_load_lds(
                (const AS1 unsigned int*)(g + so + lane * 16),
                (AS3 unsigned int*)(smem + XS_OFF + dof), 16, 0, 0);
        }
    };
    auto issueB = [&](int bb) {
        const char* g = (const char*)(x + (size_t)bb * 12288);
        #pragma unroll
        for (int i = 0; i < 4; ++i) {
            int idx = w * 4 + i;                   // 0..31
            if (idx >= 27) idx -= 27;              // dummy -> dup 0..4
            const int ic = idx / 9, k = idx - ic * 9;
            const int so  = ic * 16384 + ((k == 0) ? 7936 : 8192 + (k - 1) * 1024);
            const int dof = ic * 8448  + ((k == 0) ? 0    : 256  + (k - 1) * 1024);
            __builtin_amdgcn_global_load_lds(
                (const AS1 unsigned int*)(g + so + lane * 16),
                (AS3 unsigned int*)(smem + XSB_OFF + dof), 16, 0, 0);
        }
    };

    auto im2col = [&](int half) {
        const int p  = tid;
        const int oy = half * 16 + (p >> 5);
        const int ox = p & 31;
        const int bx = 2 * ox;
        float f[32];
        #pragma unroll
        for (int ic = 0; ic < 3; ++ic) {
            #pragma unroll
            for (int ky = 0; ky < 3; ++ky) {
                const int  iy  = 2 * oy + ky - 1;
                const bool oky = iy >= 0;
                const float* rowp = (half == 0)
                    ? xs  + ic * 2048 + (oky ? iy : 0) * 64      // rows 0..31
                    : xsb + ic * 2112 + (iy - 31) * 64;          // rows 31..63
                const float2 p12 = *(const float2*)(rowp + bx);
                const float2 pm  = *(const float2*)(rowp + (bx >= 2 ? bx - 2 : 0));
                const int k = ic * 9 + ky * 3;
                f[k + 0] = (oky && ox > 0) ? pm.y : 0.f;
                f[k + 1] = oky ? p12.x : 0.f;
                f[k + 2] = oky ? p12.y : 0.f;
            }
        }
        f[27] = 0.f; f[28] = 0.f; f[29] = 0.f; f[30] = 0.f; f[31] = 0.f;
        unsigned pk[16];
        #pragma unroll
        for (int t = 0; t < 16; ++t) pk[t] = pkbf2(f[2 * t], f[2 * t + 1]);
        uint4* dst = (uint4*)(a1 + p * A1STR);
        dst[0] = make_uint4(pk[0],  pk[1],  pk[2],  pk[3]);
        dst[1] = make_uint4(pk[4],  pk[5],  pk[6],  pk[7]);
        dst[2] = make_uint4(pk[8],  pk[9],  pk[10], pk[11]);
        dst[3] = make_uint4(pk[12], pk[13], pk[14], pk[15]);
    };

    auto conv1_mfma = [&](int half) {
        #pragma unroll
        for (int i = 0; i < 2; ++i) {
            const int t = w * 2 + i;
            const char* abase = a1 + (t * 32 + col) * A1STR + ss * 16;
            const short8 bf0 = *(const short8*)(abase);
            const short8 bf1 = *(const short8*)(abase + 32);
            floatx16 acc;
            #pragma unroll
            for (int r = 0; r < 16; ++r) acc[r] = 0.f;
            acc = __builtin_amdgcn_mfma_f32_32x32x16_bf16(w1f[0], bf0, acc, 0, 0, 0);
            acc = __builtin_amdgcn_mfma_f32_32x32x16_bf16(w1f[1], bf1, acc, 0, 0, 0);
            const int oyg = half * 16 + t;
            char* hb = h1b + oyg * ROWB + wbase;
            #pragma unroll
            for (int rp = 0; rp < 8; ++rp) {
                const unsigned u = pkbf2(fmaxf(acc[2 * rp]     + b1p[rp].x, 0.f),
                                         fmaxf(acc[2 * rp + 1] + b1p[rp].y, 0.f));
                const int off = (((rp >> 1) ^ wswz) << 4) + (rp & 1) * 4;
                *(unsigned*)(hb + off) = u;
            }
        }
    };

    // prologue: A(0)+B(0) in flight + dummy store -> queue {A3,B4,ST}
    issueA(blockIdx.x);
    issueB(blockIdx.x);
    CFENCE();
    if (lane < 8) pooled[(size_t)blockIdx.x * 64 + w * 8 + lane] = 0.f;
    CFENCE();
    BAR_VM5();            // A(0) ready (retire oldest 3 = A); B+ST fly
    im2col(0);            // a1(0) from xsA(0)
    BAR_LGKM();           // all waves' xsA(0) reads retired (issueA(1) next)

    #pragma unroll 1
    for (int s = 0; s < SPB; ++s) {
        const int b  = blockIdx.x + (s << 8);
        const int bn = (s + 1 < SPB) ? b + 256 : b;   // tail: reload self

        issueA(bn);       // xsA(s) readers drained at prologue/iter-end lgkm
        conv1_mfma(0);    // reads a1 (wave-local), writes h1b rows 0..15
        BAR_VM4();        // B(s) ready (retire B x4; keep {ST, A x3})
        im2col(1);        // reads xsB(s), writes a1
        conv1_mfma(1);    // wave-local a1 reads, writes h1b rows 16..31
        BAR_FULL();       // h1b complete + A(s+1) ready (queue is old: cheap)

        // ---- merged region: conv2(s) + pool(s) + im2col0(s+1) ----
        if (s + 1 < SPB) im2col(0);   // a1(s+1) from xsA(s+1); disjoint from h1b

        const int t0 = w >> 1;
        float pool = 0.f;
        floatx16 acc0, acc1;
        #pragma unroll
        for (int r = 0; r < 16; ++r) { acc0[r] = 0.f; acc1[r] = 0.f; }
        #pragma unroll
        for (int ky = 0; ky < 3; ++ky) {
            #pragma unroll
            for (int kx = 0; kx < 3; ++kx) {
                const int  iy0 = t0 * 4 + oyb * 2 + ky - 1;
                const bool ok0 = okx[kx] && (iy0 >= 0);
                const bool ok1 = okx[kx];
                const int  ba0 = iy0 * ROWB;
                const int  ba1 = ba0 + 16 * ROWB;
                #pragma unroll
                for (int h = 0; h < 2; ++h) {
                    const int so = sbv[kx][h];
                    short8 a0v = ok0 ? *(const short8*)(h1b + ba0 + so) : z8;
                    short8 a1v = ok1 ? *(const short8*)(h1b + ba1 + so) : z8;
                    const short8 bf = bfr[ky * 3 + kx][h];
                    acc0 = __builtin_amdgcn_mfma_f32_32x32x16_bf16(a0v, bf, acc0, 0, 0, 0);
                    acc1 = __builtin_amdgcn_mfma_f32_32x32x16_bf16(a1v, bf, acc1, 0, 0, 0);
                }
            }
        }
        issueB(bn);       // xsB(s) readers drained at BAR_FULL above
        #pragma unroll
        for (int r = 0; r < 16; ++r) {
            pool += fmaxf(acc0[r] + bias2, 0.f);
            pool += fmaxf(acc1[r] + bias2, 0.f);
        }
        pool += __shfl_xor(pool, 32, 64);
        if (lane < 32) poolbuf[w * 32 + lane] = pool;
        BAR_LGKM();       // conv2 h1b reads retired + poolbuf + a1(s+1) visible
        if (lane < 8) {   // distributed store: 1 per wave (uniform vmcnt)
            const int ch = w * 8 + lane;
            const int g = ch >> 5, c = ch & 31;
            pooled[(size_t)b * 64 + ch] =
                (poolbuf[(g    ) * 32 + c] + poolbuf[(g + 2) * 32 + c] +
                 poolbuf[(g + 4) * 32 + c] + poolbuf[(g + 6) * 32 + c]) * (1.f / 256.f);
        }
    }
}

// ---------------------------------------------------------------------------
// k_mlp: 256 blocks x 16 samples, all shared-weight layers via MFMA 16x16x32.
// (unchanged from R4)
// ---------------------------------------------------------------------------
#define ML_BIAS_B 115712
#define ML_P_SH   59392
#define ML_A_SH   60544
#define ML_B_SH   64768
#define ML_Z_F    34496
#define ML_SMEM   142336

__global__ __launch_bounds__(256, 1) void k_mlp(
    const char* __restrict__ wsblk,   // d_ws + WS_MLP_B (staged verbatim)
    const float* __restrict__ pooled, const float* __restrict__ C,
    float* __restrict__ out)
{
    __shared__ __align__(16) char smem[ML_SMEM];
    short*       Sw   = (short*)smem;
    const short* S    = (const short*)smem;
    const float* Bias = (const float*)(smem + ML_BIAS_B);
    float*       Zf   = (float*)smem;     // indexed from ML_Z_F

    const int tid    = threadIdx.x;
    const int lane   = tid & 63;
    const int w      = tid >> 6;
    const int n16    = lane & 15;
    const int q      = lane >> 4;
    const int tile16 = blockIdx.x * 16;

    // ---- stage weights+biases: 29 * 4096 B, exact, via global_load_lds ----
    #pragma unroll
    for (int i = 0; i < 29; ++i) {
        const int off = i * 4096 + w * 1024;
        __builtin_amdgcn_global_load_lds(
            (const AS1 unsigned int*)(wsblk + off + lane * 16),
            (AS3 unsigned int*)(smem + off), 16, 0, 0);
    }
    // ---- stage pooled tile -> P bf16 [16][72] ----
    {
        const float4 pv = *(const float4*)(pooled + tile16 * 64 + tid * 4);
        const int s = tid >> 4, k = (tid & 15) * 4;
        uint2 u;
        u.x = pkbf2(pv.x, pv.y);
        u.y = pkbf2(pv.z, pv.w);
        *(uint2*)(Sw + ML_P_SH + s * 72 + k) = u;
    }
    BAR_FULL();   // weights + pooled visible

    // ---- generic MFMA layer ----
    auto layer = [&](int inOff, int inPitch, int K, int wOff, int nTiles,
                     int biasOff, int outOff, bool isOut) {
        #pragma unroll
        for (int nt = w; nt < nTiles; nt += 4) {
            floatx4 acc;
            acc[0] = 0.f; acc[1] = 0.f; acc[2] = 0.f; acc[3] = 0.f;
            const int kp = K + 8;
            #pragma unroll
            for (int kc = 0; kc < 8; ++kc) {        // K/32 chunks (max 8)
                if (kc * 32 >= K) break;
                const short8 aF = *(const short8*)(S + inOff + n16 * inPitch + kc * 32 + q * 8);
                const short8 bF = *(const short8*)(S + wOff + (nt * 16 + n16) * kp + kc * 32 + q * 8);
                acc = __builtin_amdgcn_mfma_f32_16x16x32_bf16(aF, bF, acc, 0, 0, 0);
            }
            const int   n  = nt * 16 + n16;
            const float bv = Bias[biasOff + n];
            #pragma unroll
            for (int r = 0; r < 4; ++r) {
                const int   m = q * 4 + r;
                const float v = fmaxf(acc[r] + bv, 0.f);
                if (isOut) Zf[ML_Z_F + m * 68 + n] = (n < 50) ? v : -1e30f;
                else       Sw[outOff + m * 264 + n] = f2bf(v);
            }
        }
    };

    layer(ML_P_SH, 72, 64, 0, 8, 0, ML_A_SH, false);            // enc -> x1 (A 0..127)
    BAR_LGKM();
    layer(ML_A_SH, 264, 128, 9216, 4, 128, ML_B_SH, false);     // f1 -> x2 (B 0..63)
    BAR_LGKM();

    // ---- einsum: e[s][i] = sum_j C[b][i][j] * x2[s][j], 800 items ----
    #pragma unroll
    for (int r = 0; r < 4; ++r) {
        const int item = tid + r * 256;
        if (item < 800) {
            const int s = (item * 1311) >> 16;      // item/50, exact for <800
            const int i = item - s * 50;
            const float* Cp = C + (size_t)(tile16 + s) * 2500 + i * 50;
            float e = 0.f;
            #pragma unroll
            for (int j2 = 0; j2 < 25; ++j2) {
                const float2   cc = *(const float2*)(Cp + 2 * j2);
                const unsigned u  = *(const unsigned*)(S + ML_B_SH + s * 264 + 2 * j2);
                e += cc.x * __uint_as_float(u << 16)
                   + cc.y * __uint_as_float(u & 0xffff0000u);
            }
            Sw[ML_B_SH + s * 264 + 64 + i] = f2bf(e);
        }
    }
    if ((tid & 15) < 14)                              // zero-pad e[50..63]
        Sw[ML_B_SH + (tid >> 4) * 264 + 64 + 50 + (tid & 15)] = 0;
    BAR_LGKM();

    layer(ML_B_SH + 64, 264, 64, 17920, 8, 192, ML_A_SH + 128, false); // f2 -> x3 (A 128..255)
    BAR_LGKM();
    layer(ML_A_SH, 264, 256, 27136, 4, 320, ML_B_SH, false);    // f3 (concat) -> x5 (B 0..63)
    BAR_LGKM();
    layer(ML_B_SH, 264, 64, 44032, 4, 384, ML_B_SH + 64, false);// f4 -> x6 (B 64..127)
    BAR_LGKM();
    layer(ML_B_SH + 64, 264, 64, 48640, 4, 448, ML_B_SH + 128, false); // f5 -> x7
    BAR_LGKM();
    layer(ML_B_SH + 128, 264, 64, 53248, 4, 512, 0, true);      // out -> Z (fp32)
    BAR_LGKM();

    // ---- softmax: 16 threads per sample, 4 logits each, width-16 shuffles ----
    {
        const int s = tid >> 4, g = tid & 15;
        const float4 zv = *(const float4*)(Zf + ML_Z_F + s * 68 + g * 4);
        float m = fmaxf(fmaxf(zv.x, zv.y), fmaxf(zv.z, zv.w));
        #pragma unroll
        for (int o = 8; o > 0; o >>= 1) m = fmaxf(m, __shfl_xor(m, o, 16));
        float4 p;
        p.x = __expf(zv.x - m); p.y = __expf(zv.y - m);
        p.z = __expf(zv.z - m); p.w = __expf(zv.w - m);
        float sum = p.x + p.y + p.z + p.w;
        #pragma unroll
        for (int o = 8; o > 0; o >>= 1) sum += __shfl_xor(sum, o, 16);
        const float inv = 1.f / sum;
        float* po = out + (size_t)(tile16 + s) * 50 + g * 4;
        const int j = g * 4;
        if (j     < 50) po[0] = p.x * inv;
        if (j + 1 < 50) po[1] = p.y * inv;
        if (j + 2 < 50) po[2] = p.z * inv;
        if (j + 3 < 50) po[3] = p.w * inv;
    }
}

// ---------------------------------------------------------------------------
extern "C" void kernel_launch(void* const* d_in, const int* in_sizes, int n_in,
                              void* d_out, int out_size, void* d_ws, size_t ws_size,
                              hipStream_t stream) {
    (void)in_sizes; (void)n_in; (void)out_size; (void)ws_size;
    const float* x   = (const float*)d_in[0];
    const float* Cm  = (const float*)d_in[1];
    const float* c1w = (const float*)d_in[2];
    const float* c1b = (const float*)d_in[3];
    const float* c2w = (const float*)d_in[4];
    const float* c2b = (const float*)d_in[5];
    const float* ew  = (const float*)d_in[6];
    const float* ebv = (const float*)d_in[7];
    const float* f1w = (const float*)d_in[8];
    const float* f1b = (const float*)d_in[9];
    const float* f2w = (const float*)d_in[10];
    const float* f2b = (const float*)d_in[11];
    const float* f3w = (const float*)d_in[12];
    const float* f3b = (const float*)d_in[13];
    const float* f4w = (const float*)d_in[14];
    const float* f4b = (const float*)d_in[15];
    const float* f5w = (const float*)d_in[16];
    const float* f5b = (const float*)d_in[17];
    const float* ow  = (const float*)d_in[18];
    const float* ob  = (const float*)d_in[19];

    short* packw   = (short*)d_ws;
    float* biasout = (float*)((char*)d_ws + WS_BIAS_B);
    float* pooled  = (float*)((char*)d_ws + WS_POOL_B);
    const char* wsblk = (const char*)d_ws + WS_MLP_B;
    float* out     = (float*)d_out;

    hipLaunchKernelGGL(k_prep, dim3(305), dim3(256), 0, stream,
                       c2w, c1w, ew, f1w, f2w, f3w, f4w, f5w, ow,
                       ebv, f1b, f2b, f3b, f4b, f5b, ob, packw, biasout);
    hipLaunchKernelGGL(k_conv, dim3(256), dim3(512), 0, stream,
                       x, c1b, packw, c2b, pooled);
    hipLaunchKernelGGL(k_mlp,  dim3(256), dim3(256), 0, stream,
                       wsblk, pooled, Cm, out);
}